// Round 11
// baseline (2389.670 us; speedup 1.0000x reference)
//
#include <hip/hip_runtime.h>
#include <hip/hip_bf16.h>

typedef unsigned short u16;
typedef __attribute__((ext_vector_type(4))) float f32x4;
typedef __attribute__((ext_vector_type(8))) short bf16x8;
typedef __attribute__((ext_vector_type(8))) u16 u16x8;

#define GLDS16(g, l) __builtin_amdgcn_global_load_lds( \
    (const __attribute__((address_space(1))) void*)(g), \
    (__attribute__((address_space(3))) void*)(l), 16, 0, 0)

__device__ inline u16 f2bf(float f) {
  union { float f; unsigned u; } v; v.f = f;
  unsigned r = v.u + 0x7fffu + ((v.u >> 16) & 1u);
  return (u16)(r >> 16);
}

// ---------------------------------------------------------------------------
// Kernel 1: W[o][i] = (q[o][i]-8)*scale[o][i/32] + sum_r la[o][r]*lb[r][i]
// ---------------------------------------------------------------------------
__global__ __launch_bounds__(256) void k_dequant_lora(
    const int* __restrict__ qw, const float* __restrict__ sc,
    const float* __restrict__ la, const float* __restrict__ lb,
    u16* __restrict__ W)
{
  const int I = 4096, R = 16;
  __shared__ float lbs[16][512];
  __shared__ float las[256];
  const int c0 = blockIdx.x * 512;
  const int o0 = blockIdx.y * 16;
  const int tid = threadIdx.x;

  las[tid] = la[(size_t)(o0 + (tid >> 4)) * R + (tid & 15)];
  #pragma unroll
  for (int i = 0; i < 8; ++i) {
    int idx = tid + i * 256;
    int r = idx >> 7;
    int cc4 = (idx & 127) << 2;
    *(float4*)&lbs[r][cc4] = *(const float4*)&lb[(size_t)r * I + c0 + cc4];
  }
  __syncthreads();

  const int cc = (tid & 63) * 8;
  const int rg = tid >> 6;
  #pragma unroll
  for (int rr = 0; rr < 4; ++rr) {
    const int o = o0 + rg * 4 + rr;
    float acc[8] = {0.f,0.f,0.f,0.f,0.f,0.f,0.f,0.f};
    #pragma unroll
    for (int r = 0; r < 16; ++r) {
      float av = las[(rg * 4 + rr) * 16 + r];
      float4 b0 = *(const float4*)&lbs[r][cc];
      float4 b1 = *(const float4*)&lbs[r][cc + 4];
      acc[0] += av * b0.x; acc[1] += av * b0.y;
      acc[2] += av * b0.z; acc[3] += av * b0.w;
      acc[4] += av * b1.x; acc[5] += av * b1.y;
      acc[6] += av * b1.z; acc[7] += av * b1.w;
    }
    const int4* qp = (const int4*)&qw[(size_t)o * I + c0 + cc];
    int4 q0 = qp[0], q1 = qp[1];
    float s = sc[(size_t)o * (I / 32) + ((c0 + cc) >> 5)];
    u16x8 w;
    w[0] = f2bf(((float)q0.x - 8.0f) * s + acc[0]);
    w[1] = f2bf(((float)q0.y - 8.0f) * s + acc[1]);
    w[2] = f2bf(((float)q0.z - 8.0f) * s + acc[2]);
    w[3] = f2bf(((float)q0.w - 8.0f) * s + acc[3]);
    w[4] = f2bf(((float)q1.x - 8.0f) * s + acc[4]);
    w[5] = f2bf(((float)q1.y - 8.0f) * s + acc[5]);
    w[6] = f2bf(((float)q1.z - 8.0f) * s + acc[6]);
    w[7] = f2bf(((float)q1.w - 8.0f) * s + acc[7]);
    *(u16x8*)&W[(size_t)o * I + c0 + cc] = w;
  }
}

// ---------------------------------------------------------------------------
// Kernel 2: x (f32) -> bf16
// ---------------------------------------------------------------------------
__global__ __launch_bounds__(256) void k_cvt(const float* __restrict__ x,
                                             u16* __restrict__ xb)
{
  const size_t n = (size_t)8192 * 4096;
  const size_t stride = (size_t)gridDim.x * 256 * 8;
  for (size_t i = ((size_t)blockIdx.x * 256 + threadIdx.x) * 8; i < n; i += stride) {
    float4 a = *(const float4*)&x[i];
    float4 b = *(const float4*)&x[i + 4];
    u16x8 o;
    o[0] = f2bf(a.x); o[1] = f2bf(a.y); o[2] = f2bf(a.z); o[3] = f2bf(a.w);
    o[4] = f2bf(b.x); o[5] = f2bf(b.y); o[6] = f2bf(b.z); o[7] = f2bf(b.w);
    *(u16x8*)&xb[i] = o;
  }
}

// ---------------------------------------------------------------------------
// Kernel 3: C[M,N] = A[M,K] @ B[N,K]^T + bias
// Round-11: OCCUPANCY. Rounds 3/4/10 mapped the sync axis at 1 block/CU
// (249/287/257us) -> all schedules converge when every wave syncs on the
// same barrier; occupancy (21%) is the binding constraint, not phasing.
// Change: 4-ring -> 2-ring LDS (128KB -> 64KB) => 2 blocks/CU co-resident
// (512 blocks = exactly 2/CU, no tail). Depth-1 prefetch with vmcnt(0)
// per tile is a worse single-block schedule, but the co-resident block's
// MFMA covers every drain (m114 mechanism; m132's occupancy lesson).
// Per tile: bar -> STAGE(t+1,nxt) -> ds_read 12 frags(cur) -> lgkm0 ->
// 32 MFMA -> vmcnt(0). launch_bounds(512,4) pins VGPR<=128 so 4 waves/SIMD
// materialize. Layout/staging/epilogue = round-3 (0 conflicts measured).
// ---------------------------------------------------------------------------
__global__ __launch_bounds__(512, 4) void k_gemm(
    const u16* __restrict__ A, const u16* __restrict__ B,
    const float* __restrict__ bias, float* __restrict__ C)
{
  const int N = 4096, K = 4096;
  const int NTK = 128;                 // K / 32
  __shared__ u16 As[2 * 8192];         // 2 ring buffers x [256 rows][32 k]
  __shared__ u16 Bs[2 * 8192];

  // XCD swizzle: 512 blocks = 8 XCDs x 64
  const int bid = blockIdx.x;
  const int swz = (bid & 7) * 64 + (bid >> 3);
  const int m0 = (swz >> 4) * 256;     // 32 M-tiles
  const int n0 = (swz & 15) * 256;     // 16 N-tiles

  const int tid = threadIdx.x;
  const int wid = tid >> 6, lane = tid & 63;
  const int wid_m = wid >> 2, wid_n = wid & 3;

  // staging geometry (round-3, refcheck-passed, 0 conflicts measured)
  const int st0 = wid;
  const int st1 = 8 + wid;
  const int srow = lane >> 2;
  const int schunk = (((lane & 3) ^ (((lane >> 5) & 1) << 1))) * 8;
  const u16* Asrc0 = A + (size_t)(m0 + st0 * 16 + srow) * K + schunk;
  const u16* Asrc1 = A + (size_t)(m0 + st1 * 16 + srow) * K + schunk;
  const u16* Bsrc0 = B + (size_t)(n0 + st0 * 16 + srow) * K + schunk;
  const u16* Bsrc1 = B + (size_t)(n0 + st1 * 16 + srow) * K + schunk;

#define STAGE_A(buf, t) do { \
    GLDS16(Asrc0 + (size_t)(t) * 32, &As[(buf) * 8192 + st0 * 512]); \
    GLDS16(Asrc1 + (size_t)(t) * 32, &As[(buf) * 8192 + st1 * 512]); } while (0)
#define STAGE_B(buf, t) do { \
    GLDS16(Bsrc0 + (size_t)(t) * 32, &Bs[(buf) * 8192 + st0 * 512]); \
    GLDS16(Bsrc1 + (size_t)(t) * 32, &Bs[(buf) * 8192 + st1 * 512]); } while (0)

  // round-3 fragment read offset (measured 0 bank conflicts)
  const int LA = (lane & 15) * 32 + (((lane >> 4) * 8) ^ ((lane & 8) ? 16 : 0));
  const int wmb = wid_m * 8;           // A frag base (8 m-frags per wave)
  const int wnb = wid_n * 4;           // B frag base (4 n-frags per wave)

  f32x4 acc[8][4] = {};
  bf16x8 af[8], bf[4];

  // ---- prologue: stage tile 0 into buf0; ensure landed ----
  STAGE_A(0, 0); STAGE_B(0, 0);
  asm volatile("s_waitcnt vmcnt(0)" ::: "memory");

  for (int t = 0; t < NTK; ++t) {
    const int cur = t & 1;
    __builtin_amdgcn_s_barrier();      // tile t published; prev reads done
    __builtin_amdgcn_sched_barrier(0);

    // issue next-tile staging FIRST (longest latency)
    if (t + 1 < NTK) {
      STAGE_A(cur ^ 1, t + 1);
      STAGE_B(cur ^ 1, t + 1);
    }
    // fragment reads from current buffer
    #pragma unroll
    for (int m = 0; m < 8; ++m)
      af[m] = *(const bf16x8*)&As[cur * 8192 + (wmb + m) * 512 + LA];
    #pragma unroll
    for (int n = 0; n < 4; ++n)
      bf[n] = *(const bf16x8*)&Bs[cur * 8192 + (wnb + n) * 512 + LA];

    __builtin_amdgcn_sched_barrier(0);
    asm volatile("s_waitcnt lgkmcnt(0)" ::: "memory");
    __builtin_amdgcn_sched_barrier(0);
    __builtin_amdgcn_s_setprio(1);
    #pragma unroll
    for (int m = 0; m < 8; ++m)
      #pragma unroll
      for (int n = 0; n < 4; ++n)
        acc[m][n] = __builtin_amdgcn_mfma_f32_16x16x32_bf16(af[m], bf[n], acc[m][n], 0, 0, 0);
    __builtin_amdgcn_s_setprio(0);
    __builtin_amdgcn_sched_barrier(0);
    asm volatile("s_waitcnt vmcnt(0)" ::: "memory");   // t+1 landed
  }
#undef STAGE_A
#undef STAGE_B

  // ---- epilogue: C/D layout col=lane&15, row=(lane>>4)*4+j ----
  const int crow = m0 + wid_m * 128 + ((lane >> 4) << 2);
  const int ccol = n0 + wid_n * 64 + (lane & 15);
  #pragma unroll
  for (int n = 0; n < 4; ++n) {
    float bv = bias[ccol + n * 16];
    #pragma unroll
    for (int m = 0; m < 8; ++m) {
      #pragma unroll
      for (int j = 0; j < 4; ++j) {
        C[(size_t)(crow + m * 16 + j) * N + ccol + n * 16] = acc[m][n][j] + bv;
      }
    }
  }
}

// ---------------------------------------------------------------------------
extern "C" void kernel_launch(void* const* d_in, const int* in_sizes, int n_in,
                              void* d_out, int out_size, void* d_ws, size_t ws_size,
                              hipStream_t stream) {
  const float* x    = (const float*)d_in[0];   // [8192, 4096] f32
  const int*   qw   = (const int*)d_in[1];     // [4096, 4096] i32
  const float* sc   = (const float*)d_in[2];   // [4096, 128]  f32
  const float* la   = (const float*)d_in[3];   // [4096, 16]   f32
  const float* lb   = (const float*)d_in[4];   // [16, 4096]   f32
  const float* bias = (const float*)d_in[5];   // [4096]       f32
  float* y = (float*)d_out;                    // [8192, 4096] f32

  u16* W  = (u16*)d_ws;                                        // 32 MiB
  u16* Xb = (u16*)((char*)d_ws + (size_t)32 * 1024 * 1024);    // 64 MiB

  dim3 gridD(4096 / 512, 4096 / 16);
  k_dequant_lora<<<gridD, 256, 0, stream>>>(qw, sc, la, lb, W);
  k_cvt<<<2048, 256, 0, stream>>>(x, Xb);
  const int ngemm = (8192 / 256) * (4096 / 256);   // 512
  k_gemm<<<ngemm, 512, 0, stream>>>(Xb, W, bias, y);
}

// Round 12
// 421.693 us; speedup vs baseline: 5.6669x; 5.6669x over previous
//
#include <hip/hip_runtime.h>
#include <hip/hip_bf16.h>

typedef unsigned short u16;
typedef __attribute__((ext_vector_type(4))) float f32x4;
typedef __attribute__((ext_vector_type(8))) short bf16x8;
typedef __attribute__((ext_vector_type(8))) u16 u16x8;

#define GLDS16(g, l) __builtin_amdgcn_global_load_lds( \
    (const __attribute__((address_space(1))) void*)(g), \
    (__attribute__((address_space(3))) void*)(l), 16, 0, 0)

__device__ inline u16 f2bf(float f) {
  union { float f; unsigned u; } v; v.f = f;
  unsigned r = v.u + 0x7fffu + ((v.u >> 16) & 1u);
  return (u16)(r >> 16);
}

// ---------------------------------------------------------------------------
// Kernel 1 (fused prep): each of 2048 blocks does (a) its dequant+LoRA
// 16x512 patch, then (b) its 16384-elem cvt slice. Sequential within block
// (round-8's block-range split regressed; this removes a launch instead).
// ---------------------------------------------------------------------------
__global__ __launch_bounds__(256) void k_prep(
    const int* __restrict__ qw, const float* __restrict__ sc,
    const float* __restrict__ la, const float* __restrict__ lb,
    const float* __restrict__ x,
    u16* __restrict__ W, u16* __restrict__ xb)
{
  const int I = 4096, R = 16;
  __shared__ float lbs[16][512];
  __shared__ float las[256];
  const int b = blockIdx.x;
  const int c0 = (b & 7) * 512;
  const int o0 = (b >> 3) * 16;
  const int tid = threadIdx.x;

  // ---- part 1: dequant + LoRA (identical math to rounds 1-10) ----
  las[tid] = la[(size_t)(o0 + (tid >> 4)) * R + (tid & 15)];
  #pragma unroll
  for (int i = 0; i < 8; ++i) {
    int idx = tid + i * 256;
    int r = idx >> 7;
    int cc4 = (idx & 127) << 2;
    *(float4*)&lbs[r][cc4] = *(const float4*)&lb[(size_t)r * I + c0 + cc4];
  }
  __syncthreads();

  const int cc = (tid & 63) * 8;
  const int rg = tid >> 6;
  #pragma unroll
  for (int rr = 0; rr < 4; ++rr) {
    const int o = o0 + rg * 4 + rr;
    float acc[8] = {0.f,0.f,0.f,0.f,0.f,0.f,0.f,0.f};
    #pragma unroll
    for (int r = 0; r < 16; ++r) {
      float av = las[(rg * 4 + rr) * 16 + r];
      float4 b0 = *(const float4*)&lbs[r][cc];
      float4 b1 = *(const float4*)&lbs[r][cc + 4];
      acc[0] += av * b0.x; acc[1] += av * b0.y;
      acc[2] += av * b0.z; acc[3] += av * b0.w;
      acc[4] += av * b1.x; acc[5] += av * b1.y;
      acc[6] += av * b1.z; acc[7] += av * b1.w;
    }
    const int4* qp = (const int4*)&qw[(size_t)o * I + c0 + cc];
    int4 q0 = qp[0], q1 = qp[1];
    float s = sc[(size_t)o * (I / 32) + ((c0 + cc) >> 5)];
    u16x8 w;
    w[0] = f2bf(((float)q0.x - 8.0f) * s + acc[0]);
    w[1] = f2bf(((float)q0.y - 8.0f) * s + acc[1]);
    w[2] = f2bf(((float)q0.z - 8.0f) * s + acc[2]);
    w[3] = f2bf(((float)q0.w - 8.0f) * s + acc[3]);
    w[4] = f2bf(((float)q1.x - 8.0f) * s + acc[4]);
    w[5] = f2bf(((float)q1.y - 8.0f) * s + acc[5]);
    w[6] = f2bf(((float)q1.z - 8.0f) * s + acc[6]);
    w[7] = f2bf(((float)q1.w - 8.0f) * s + acc[7]);
    *(u16x8*)&W[(size_t)o * I + c0 + cc] = w;
  }

  // ---- part 2: x f32 -> bf16, this block's 16384-elem contiguous slice ----
  const size_t base = (size_t)b * 16384;
  #pragma unroll
  for (int it = 0; it < 8; ++it) {
    size_t i = base + (size_t)it * 2048 + (size_t)tid * 8;
    float4 a = *(const float4*)&x[i];
    float4 c = *(const float4*)&x[i + 4];
    u16x8 o;
    o[0] = f2bf(a.x); o[1] = f2bf(a.y); o[2] = f2bf(a.z); o[3] = f2bf(a.w);
    o[4] = f2bf(c.x); o[5] = f2bf(c.y); o[6] = f2bf(c.z); o[7] = f2bf(c.w);
    *(u16x8*)&xb[i] = o;
  }
}

// ---------------------------------------------------------------------------
// Kernel 2: C[M,N] = A[M,K] @ B[N,K]^T + bias
// Round-12: round-3 WAR/RAW skeleton (4-ring BK=32, stage-2-ahead, counted
// vmcnt(4), 0-conflict layout, 1 blk/CU) with the tile split into 4 FINE
// phases (m196/m201 granularity lever):
//   p: { 2-6 ds_read_b128 ; 1 global_load_lds ; bar ; lgkm0 ;
//        setprio(1) ; 8 MFMA (2m x 4n) ; setprio(0) }
// vmcnt(4) once per tile at p4 before its barrier (publishes tile t+1).
// Ring aging >= 4 barriers protects WAR; identical gload count/positions
// relative to the publishing barrier as round-3.
// ---------------------------------------------------------------------------
__global__ __launch_bounds__(512, 1) void k_gemm(
    const u16* __restrict__ A, const u16* __restrict__ B,
    const float* __restrict__ bias, float* __restrict__ C)
{
  const int N = 4096, K = 4096;
  const int NTK = 128;                 // K / 32
  __shared__ u16 As[4 * 8192];         // 4 ring buffers x [256 rows][32 k]
  __shared__ u16 Bs[4 * 8192];

  // XCD swizzle: 512 blocks = 8 XCDs x 64
  const int bid = blockIdx.x;
  const int swz = (bid & 7) * 64 + (bid >> 3);
  const int m0 = (swz >> 4) * 256;     // 32 M-tiles
  const int n0 = (swz & 15) * 256;     // 16 N-tiles

  const int tid = threadIdx.x;
  const int wid = tid >> 6, lane = tid & 63;
  const int wid_m = wid >> 2, wid_n = wid & 3;

  // staging geometry (round-3, refcheck-passed, 0 conflicts measured)
  const int st0 = wid;
  const int st1 = 8 + wid;
  const int srow = lane >> 2;
  const int schunk = (((lane & 3) ^ (((lane >> 5) & 1) << 1))) * 8;
  const u16* Asrc0 = A + (size_t)(m0 + st0 * 16 + srow) * K + schunk;
  const u16* Asrc1 = A + (size_t)(m0 + st1 * 16 + srow) * K + schunk;
  const u16* Bsrc0 = B + (size_t)(n0 + st0 * 16 + srow) * K + schunk;
  const u16* Bsrc1 = B + (size_t)(n0 + st1 * 16 + srow) * K + schunk;

  // round-3 fragment read offset (measured 0 bank conflicts)
  const int LA = (lane & 15) * 32 + (((lane >> 4) * 8) ^ ((lane & 8) ? 16 : 0));
  const int wmb = wid_m * 8;           // A frag base (8 m-frags per wave)
  const int wnb = wid_n * 4;           // B frag base (4 n-frags per wave)

  f32x4 acc[8][4] = {};

  // ---- prologue: stage tiles 0,1; publish tile 0 ----
  GLDS16(Asrc0, &As[st0 * 512]);
  GLDS16(Asrc1, &As[st1 * 512]);
  GLDS16(Bsrc0, &Bs[st0 * 512]);
  GLDS16(Bsrc1, &Bs[st1 * 512]);
  GLDS16(Asrc0 + 32, &As[8192 + st0 * 512]);
  GLDS16(Asrc1 + 32, &As[8192 + st1 * 512]);
  GLDS16(Bsrc0 + 32, &Bs[8192 + st0 * 512]);
  GLDS16(Bsrc1 + 32, &Bs[8192 + st1 * 512]);
  asm volatile("s_waitcnt vmcnt(4)" ::: "memory");   // tile 0 landed
  __builtin_amdgcn_s_barrier();

  for (int t = 0; t < NTK; ++t) {
    const int b_ = t & 3;
    const int bs_ = (t + 2) & 3;
    const bool stg = (t + 2 < NTK);
    const u16* Ab = &As[b_ * 8192];
    const u16* Bb = &Bs[b_ * 8192];
    bf16x8 bfr[4], a0, a1;

    // ======== phase 1: b0-3 + a0,a1 ; gload A-slice0 ; 8 MFMA ========
    #pragma unroll
    for (int n = 0; n < 4; ++n)
      bfr[n] = *(const bf16x8*)&Bb[(wnb + n) * 512 + LA];
    a0 = *(const bf16x8*)&Ab[(wmb + 0) * 512 + LA];
    a1 = *(const bf16x8*)&Ab[(wmb + 1) * 512 + LA];
    if (stg) GLDS16(Asrc0 + (size_t)(t + 2) * 32, &As[bs_ * 8192 + st0 * 512]);
    __builtin_amdgcn_sched_barrier(0);
    __builtin_amdgcn_s_barrier();
    asm volatile("s_waitcnt lgkmcnt(0)" ::: "memory");
    __builtin_amdgcn_sched_barrier(0);
    __builtin_amdgcn_s_setprio(1);
    #pragma unroll
    for (int n = 0; n < 4; ++n) {
      acc[0][n] = __builtin_amdgcn_mfma_f32_16x16x32_bf16(a0, bfr[n], acc[0][n], 0, 0, 0);
      acc[1][n] = __builtin_amdgcn_mfma_f32_16x16x32_bf16(a1, bfr[n], acc[1][n], 0, 0, 0);
    }
    __builtin_amdgcn_s_setprio(0);

    // ======== phase 2: a2,a3 ; gload A-slice1 ; 8 MFMA ========
    a0 = *(const bf16x8*)&Ab[(wmb + 2) * 512 + LA];
    a1 = *(const bf16x8*)&Ab[(wmb + 3) * 512 + LA];
    if (stg) GLDS16(Asrc1 + (size_t)(t + 2) * 32, &As[bs_ * 8192 + st1 * 512]);
    __builtin_amdgcn_sched_barrier(0);
    __builtin_amdgcn_s_barrier();
    asm volatile("s_waitcnt lgkmcnt(0)" ::: "memory");
    __builtin_amdgcn_sched_barrier(0);
    __builtin_amdgcn_s_setprio(1);
    #pragma unroll
    for (int n = 0; n < 4; ++n) {
      acc[2][n] = __builtin_amdgcn_mfma_f32_16x16x32_bf16(a0, bfr[n], acc[2][n], 0, 0, 0);
      acc[3][n] = __builtin_amdgcn_mfma_f32_16x16x32_bf16(a1, bfr[n], acc[3][n], 0, 0, 0);
    }
    __builtin_amdgcn_s_setprio(0);

    // ======== phase 3: a4,a5 ; gload B-slice0 ; 8 MFMA ========
    a0 = *(const bf16x8*)&Ab[(wmb + 4) * 512 + LA];
    a1 = *(const bf16x8*)&Ab[(wmb + 5) * 512 + LA];
    if (stg) GLDS16(Bsrc0 + (size_t)(t + 2) * 32, &Bs[bs_ * 8192 + st0 * 512]);
    __builtin_amdgcn_sched_barrier(0);
    __builtin_amdgcn_s_barrier();
    asm volatile("s_waitcnt lgkmcnt(0)" ::: "memory");
    __builtin_amdgcn_sched_barrier(0);
    __builtin_amdgcn_s_setprio(1);
    #pragma unroll
    for (int n = 0; n < 4; ++n) {
      acc[4][n] = __builtin_amdgcn_mfma_f32_16x16x32_bf16(a0, bfr[n], acc[4][n], 0, 0, 0);
      acc[5][n] = __builtin_amdgcn_mfma_f32_16x16x32_bf16(a1, bfr[n], acc[5][n], 0, 0, 0);
    }
    __builtin_amdgcn_s_setprio(0);

    // ======== phase 4: a6,a7 ; gload B-slice1 ; vmcnt(4) ; 8 MFMA ========
    a0 = *(const bf16x8*)&Ab[(wmb + 6) * 512 + LA];
    a1 = *(const bf16x8*)&Ab[(wmb + 7) * 512 + LA];
    if (stg) {
      GLDS16(Bsrc1 + (size_t)(t + 2) * 32, &Bs[bs_ * 8192 + st1 * 512]);
      asm volatile("s_waitcnt vmcnt(4)" ::: "memory");  // tile t+1 landed
    } else {
      asm volatile("s_waitcnt vmcnt(0)" ::: "memory");
    }
    __builtin_amdgcn_sched_barrier(0);
    __builtin_amdgcn_s_barrier();                       // publishes tile t+1
    asm volatile("s_waitcnt lgkmcnt(0)" ::: "memory");
    __builtin_amdgcn_sched_barrier(0);
    __builtin_amdgcn_s_setprio(1);
    #pragma unroll
    for (int n = 0; n < 4; ++n) {
      acc[6][n] = __builtin_amdgcn_mfma_f32_16x16x32_bf16(a0, bfr[n], acc[6][n], 0, 0, 0);
      acc[7][n] = __builtin_amdgcn_mfma_f32_16x16x32_bf16(a1, bfr[n], acc[7][n], 0, 0, 0);
    }
    __builtin_amdgcn_s_setprio(0);
  }

  // ---- epilogue: C/D layout col=lane&15, row=(lane>>4)*4+j ----
  const int crow = m0 + wid_m * 128 + ((lane >> 4) << 2);
  const int ccol = n0 + wid_n * 64 + (lane & 15);
  #pragma unroll
  for (int n = 0; n < 4; ++n) {
    float bv = bias[ccol + n * 16];
    #pragma unroll
    for (int m = 0; m < 8; ++m) {
      #pragma unroll
      for (int j = 0; j < 4; ++j) {
        C[(size_t)(crow + m * 16 + j) * N + ccol + n * 16] = acc[m][n][j] + bv;
      }
    }
  }
}

// ---------------------------------------------------------------------------
extern "C" void kernel_launch(void* const* d_in, const int* in_sizes, int n_in,
                              void* d_out, int out_size, void* d_ws, size_t ws_size,
                              hipStream_t stream) {
  const float* x    = (const float*)d_in[0];   // [8192, 4096] f32
  const int*   qw   = (const int*)d_in[1];     // [4096, 4096] i32
  const float* sc   = (const float*)d_in[2];   // [4096, 128]  f32
  const float* la   = (const float*)d_in[3];   // [4096, 16]   f32
  const float* lb   = (const float*)d_in[4];   // [16, 4096]   f32
  const float* bias = (const float*)d_in[5];   // [4096]       f32
  float* y = (float*)d_out;                    // [8192, 4096] f32

  u16* W  = (u16*)d_ws;                                        // 32 MiB
  u16* Xb = (u16*)((char*)d_ws + (size_t)32 * 1024 * 1024);    // 64 MiB

  k_prep<<<2048, 256, 0, stream>>>(qw, sc, la, lb, x, W, Xb);
  const int ngemm = (8192 / 256) * (4096 / 256);   // 512
  k_gemm<<<ngemm, 512, 0, stream>>>(Xb, W, bias, y);
}